// Round 20
// baseline (117.558 us; speedup 1.0000x reference)
//
#include <hip/hip_runtime.h>
#include <hip/hip_bf16.h>

#define N_USERS 100000
#define N_ITEMS 50000
#define NNZ_EDGES 1600000
#define DIM 64

#define BSHIFT_U 7
#define BD_U 128                             // user dests per coarse bucket
#define BSHIFT_I 6
#define BD_I 64                              // item dests per coarse bucket
#define NBU ((N_USERS + BD_U - 1) / BD_U)    // 782
#define NBI ((N_ITEMS + BD_I - 1) / BD_I)    // 782
#define NB_MAX 782
#define TILE 4096                            // edges per binning tile (8/thread @512)
#define CAP 2432                             // bucket capacity (mean 2048 + 8.5 sigma)

#define PREP_GU ((N_USERS + 127) / 128)      // 782
#define PREP_GI ((N_ITEMS + 127) / 128)      // 391
#define PREP_BIN ((NNZ_EDGES + TILE - 1) / TILE) // 391

// Record layout (binned): pk = (dst_local << 25) | (src_byte_off) with
// src_byte_off = src*128 in bits 7..24. After the in-LDS sort the dl bits
// are stripped; gather addr = (char*)xw + lane*2 + e.x.

__device__ inline unsigned short f32_to_bf16(float f) {
  unsigned u = __float_as_uint(f);
  unsigned r = (u + 0x7FFFu + ((u >> 16) & 1u)) >> 16;  // RNE
  return (unsigned short)r;
}
__device__ inline float bf16_to_f32(unsigned short h) {
  return __uint_as_float((unsigned)h << 16);
}

// ---------------------------------------------------------------------------
// PREP: merged dense GEMM + two-direction binning in ONE dispatch (r17 order:
// gemm blocks first).
// ---------------------------------------------------------------------------
__global__ __launch_bounds__(512) void prep_kernel(
    const float* __restrict__ Xu, const float* __restrict__ Wu,
    unsigned short* __restrict__ Yu,
    const float* __restrict__ Xi, const float* __restrict__ Wi,
    unsigned short* __restrict__ Yi,
    const int* __restrict__ rows, const int* __restrict__ cols,
    const float* __restrict__ vals,
    int* __restrict__ cur_u, int* __restrict__ cur_i,
    uint2* __restrict__ out_u, uint2* __restrict__ out_i) {
  __shared__ char smem[49152];
  const int tid = threadIdx.x, lane = tid & 63, wid = tid >> 6;

  if (blockIdx.x < PREP_GU + PREP_GI) {
    // ------------------------- GEMM path ---------------------------------
    float* sW = (float*)smem;                       // [64][64] 16 KB
    float* sXTb = (float*)(smem + 16384);           // [2][64][64] 32 KB
    const int sub = tid >> 8;
    const int stid = tid & 255;

    const float* X; const float* W; unsigned short* Y; int nrows, row_base;
    if (blockIdx.x < PREP_GU) {
      X = Xu; W = Wu; Y = Yu; nrows = N_USERS;
      row_base = blockIdx.x * 128 + sub * 64;
    } else {
      X = Xi; W = Wi; Y = Yi; nrows = N_ITEMS;
      row_base = (blockIdx.x - PREP_GU) * 128 + sub * 64;
    }

    {
      const float4* Wv = (const float4*)W;
      float4* sWv = (float4*)sW;
      #pragma unroll
      for (int i = 0; i < 2; ++i) sWv[tid + i * 512] = Wv[tid + i * 512];
    }
    float* sXT = sXTb + sub * 64 * 64;              // [k][row]
    {
      const int r = stid & 63;
      const int k0 = (stid >> 6) * 16;
      const int grow = row_base + r;
      #pragma unroll
      for (int i = 0; i < 4; ++i) {
        float4 v = make_float4(0.f, 0.f, 0.f, 0.f);
        if (grow < nrows) v = ((const float4*)(X + (size_t)grow * DIM + k0))[i];
        sXT[(k0 + i * 4 + 0) * 64 + r] = v.x;
        sXT[(k0 + i * 4 + 1) * 64 + r] = v.y;
        sXT[(k0 + i * 4 + 2) * 64 + r] = v.z;
        sXT[(k0 + i * 4 + 3) * 64 + r] = v.w;
      }
    }
    __syncthreads();

    const int tx = stid & 15;
    const int ty = stid >> 4;
    float acc[4][4] = {{0.f}};

    #pragma unroll 8
    for (int k = 0; k < 64; ++k) {
      const float4 a = *(const float4*)&sXT[k * 64 + ty * 4];
      const float4 b = *(const float4*)&sW[k * 64 + tx * 4];
      acc[0][0] = fmaf(a.x, b.x, acc[0][0]);
      acc[0][1] = fmaf(a.x, b.y, acc[0][1]);
      acc[0][2] = fmaf(a.x, b.z, acc[0][2]);
      acc[0][3] = fmaf(a.x, b.w, acc[0][3]);
      acc[1][0] = fmaf(a.y, b.x, acc[1][0]);
      acc[1][1] = fmaf(a.y, b.y, acc[1][1]);
      acc[1][2] = fmaf(a.y, b.z, acc[1][2]);
      acc[1][3] = fmaf(a.y, b.w, acc[1][3]);
      acc[2][0] = fmaf(a.z, b.x, acc[2][0]);
      acc[2][1] = fmaf(a.z, b.y, acc[2][1]);
      acc[2][2] = fmaf(a.z, b.z, acc[2][2]);
      acc[2][3] = fmaf(a.z, b.w, acc[2][3]);
      acc[3][0] = fmaf(a.w, b.x, acc[3][0]);
      acc[3][1] = fmaf(a.w, b.y, acc[3][1]);
      acc[3][2] = fmaf(a.w, b.z, acc[3][2]);
      acc[3][3] = fmaf(a.w, b.w, acc[3][3]);
    }

    #pragma unroll
    for (int r = 0; r < 4; ++r) {
      const int grow = row_base + ty * 4 + r;
      if (grow < nrows) {
        ushort4 o;
        o.x = f32_to_bf16(acc[r][0]);
        o.y = f32_to_bf16(acc[r][1]);
        o.z = f32_to_bf16(acc[r][2]);
        o.w = f32_to_bf16(acc[r][3]);
        *(ushort4*)(Y + (size_t)grow * DIM + tx * 4) = o;
      }
    }
    return;
  }

  // --------------------------- binning path ------------------------------
  uint2* sbuf = (uint2*)smem;                          // 32 KB
  unsigned short* sbk = (unsigned short*)(smem + 32768); // 8 KB
  int* sh   = (int*)(smem + 40960);
  int* scnt = (int*)(smem + 44088);
  int* s_w  = (int*)(smem + 47232);                    // 9 ints

  const int tbase = (blockIdx.x - (PREP_GU + PREP_GI)) * TILE;
  const int total = min(TILE, NNZ_EDGES - tbase);

  int er[8], ec[8]; unsigned ev[8];
  #pragma unroll
  for (int k = 0; k < 8; ++k) {
    const int i = tbase + k * 512 + tid;
    if (i < NNZ_EDGES) {
      er[k] = rows[i];
      ec[k] = cols[i];
      ev[k] = __float_as_uint(vals[i]);
    } else {
      er[k] = -1; ec[k] = 0; ev[k] = 0;
    }
  }

#define BIN_PHASE(BKEXPR, PKEXPR, NB, CUR, OUT)                                \
  {                                                                            \
    for (int j = tid; j < (NB); j += 512) sh[j] = 0;                           \
    __syncthreads();                                                           \
    int bk[8]; unsigned pk[8];                                                 \
    _Pragma("unroll")                                                          \
    for (int k = 0; k < 8; ++k) {                                              \
      if (er[k] >= 0) {                                                        \
        bk[k] = (BKEXPR); pk[k] = (PKEXPR);                                    \
        atomicAdd(&sh[bk[k]], 1);                                              \
      } else { bk[k] = -1; pk[k] = 0; }                                        \
    }                                                                          \
    __syncthreads();                                                           \
    int carry = 0;                                                             \
    for (int cb = 0; cb < (NB); cb += 512) {                                   \
      const int idx = cb + tid;                                                \
      const int x = (idx < (NB)) ? sh[idx] : 0;                                \
      int incl = x;                                                            \
      _Pragma("unroll")                                                        \
      for (int d = 1; d < 64; d <<= 1) {                                       \
        int t = __shfl_up(incl, d);                                            \
        if (lane >= d) incl += t;                                              \
      }                                                                        \
      if (lane == 63) s_w[wid] = incl;                                         \
      __syncthreads();                                                         \
      if (tid == 0) {                                                          \
        int a = 0;                                                             \
        _Pragma("unroll")                                                      \
        for (int w = 0; w < 8; ++w) { const int t = s_w[w]; s_w[w] = a; a += t; } \
        s_w[8] = a;                                                            \
      }                                                                        \
      __syncthreads();                                                         \
      const int excl = carry + s_w[wid] + incl - x;                            \
      if (idx < (NB)) { scnt[idx] = x; sh[idx] = excl; }                       \
      carry += s_w[8];                                                         \
      __syncthreads();                                                         \
    }                                                                          \
    _Pragma("unroll")                                                          \
    for (int k = 0; k < 8; ++k) {                                              \
      if (bk[k] >= 0) {                                                        \
        const int p = atomicAdd(&sh[bk[k]], 1);                                \
        sbuf[p] = make_uint2(pk[k], ev[k]);                                    \
        sbk[p] = (unsigned short)bk[k];                                        \
      }                                                                        \
    }                                                                          \
    __syncthreads();                                                           \
    for (int idx = tid; idx < (NB); idx += 512) {                              \
      const int c = scnt[idx];                                                 \
      const int excl = sh[idx] - c;                                            \
      int g = 0;                                                               \
      if (c > 0) g = atomicAdd(&(CUR)[idx], c);                                \
      scnt[idx] = excl;                                                        \
      sh[idx] = idx * CAP + g;                                                 \
    }                                                                          \
    __syncthreads();                                                           \
    for (int p = tid; p < total; p += 512) {                                   \
      const int b = sbk[p];                                                    \
      (OUT)[sh[b] + (p - scnt[b])] = sbuf[p];                                  \
    }                                                                          \
    __syncthreads();                                                           \
  }

  BIN_PHASE(er[k] >> BSHIFT_U,
            ((unsigned)(er[k] & (BD_U - 1)) << 25) | ((unsigned)ec[k] << 7),
            NBU, cur_u, out_u)
  BIN_PHASE(ec[k] >> BSHIFT_I,
            ((unsigned)(ec[k] & (BD_I - 1)) << 25) | ((unsigned)er[k] << 7),
            NBI, cur_i, out_i)
#undef BIN_PHASE
}

// ---------------------------------------------------------------------------
// Fused fine-sort + SpMM + ReLU. NEW: 256-thread blocks (4 waves) on the
// same coarse buckets -> 7 blocks/CU (LDS-bound) instead of 4 (thread-bound)
// => more resident waves for gather-latency hiding + finer barriers.
// Register staging rg[10] (2560 >= CAP). Gather loop unchanged (ILP-16).
// ---------------------------------------------------------------------------
__global__ __launch_bounds__(256) void sort_spmm_kernel(
    const uint2* __restrict__ bin_u, const int* __restrict__ cur_u,
    const unsigned short* __restrict__ xw_item, float* __restrict__ out_user,
    const uint2* __restrict__ bin_i, const int* __restrict__ cur_i,
    const unsigned short* __restrict__ xw_user, float* __restrict__ out_item) {
  __shared__ uint2 sbuf[CAP];     // 19.5 KB (sorted records, dl stripped)
  __shared__ int cnt[128];        // hist -> scatter cursor -> row end
  __shared__ int roff[128];       // row start
  __shared__ int s_w[2];
  const int tid = threadIdx.x;
  const int lane = tid & 63, wid = tid >> 6;   // wid 0..3

  const uint2* bin; const int* cur; const unsigned short* xw; float* out;
  int b, bd, ndst;
  if (blockIdx.x < NBU) {
    b = blockIdx.x; bd = BD_U; ndst = N_USERS;
    bin = bin_u; cur = cur_u; xw = xw_item; out = out_user;
  } else {
    b = blockIdx.x - NBU; bd = BD_I; ndst = N_ITEMS;
    bin = bin_i; cur = cur_i; xw = xw_user; out = out_item;
  }
  const int beg = b * CAP;
  const int n = min(cur[b], CAP);   // cursor holds the COUNT (offset-based)

  if (tid < 128) cnt[tid] = 0;
  __syncthreads();

  // Stage records in registers + LDS histogram of local dests.
  uint2 rg[10];
  #pragma unroll
  for (int k = 0; k < 10; ++k) {
    const int i = k * 256 + tid;
    if (i < n) {
      rg[k] = bin[beg + i];
      atomicAdd(&cnt[rg[k].x >> 25], 1);
    } else {
      rg[k] = make_uint2(0u, 0u);
    }
  }
  __syncthreads();

  // Exclusive scan of cnt[0..bd) in the first 128 threads (bd <= 128).
  int x = 0, incl = 0;
  if (tid < 128) {
    x = (tid < bd) ? cnt[tid] : 0;
    incl = x;
    #pragma unroll
    for (int d = 1; d < 64; d <<= 1) {
      int t = __shfl_up(incl, d);
      if (lane >= d) incl += t;
    }
    if (lane == 63) s_w[wid] = incl;
  }
  __syncthreads();
  if (tid == 0) {
    const int t0 = s_w[0];
    s_w[0] = 0;
    s_w[1] = t0;
  }
  __syncthreads();
  if (tid < 128) {
    const int excl = s_w[wid] + incl - x;
    if (tid < bd) {
      roff[tid] = excl;   // row start
      cnt[tid] = excl;    // scatter cursor (becomes row end after scatter)
    }
  }
  __syncthreads();

  // Scatter registers -> sorted LDS buffer, stripping the dl bits.
  #pragma unroll
  for (int k = 0; k < 10; ++k) {
    const int i = k * 256 + tid;
    if (i < n) {
      const int p = atomicAdd(&cnt[rg[k].x >> 25], 1);
      sbuf[p] = make_uint2(rg[k].x & 0x01FFFF80u, rg[k].y);
    }
  }
  __syncthreads();

  // SpMM: wave w handles rows w, w+4, ... ; lane = feature; mask-free gather.
  const char* __restrict__ xwb = (const char*)xw + lane * 2;
  for (int r = wid; r < bd; r += 4) {
    const int rb = roff[r], re = cnt[r];
    float acc = 0.f;
    int j = rb;
    for (; j + 16 <= re; j += 16) {
      uint2 e[16];
      #pragma unroll
      for (int q = 0; q < 16; ++q) e[q] = sbuf[j + q];   // LDS broadcast
      unsigned short h[16];
      #pragma unroll
      for (int q = 0; q < 16; ++q)
        h[q] = *(const unsigned short*)(xwb + e[q].x);
      #pragma unroll
      for (int q = 0; q < 16; ++q)
        acc = fmaf(__uint_as_float(e[q].y), bf16_to_f32(h[q]), acc);
    }
    for (; j + 8 <= re; j += 8) {
      uint2 e[8];
      #pragma unroll
      for (int q = 0; q < 8; ++q) e[q] = sbuf[j + q];
      unsigned short h[8];
      #pragma unroll
      for (int q = 0; q < 8; ++q)
        h[q] = *(const unsigned short*)(xwb + e[q].x);
      #pragma unroll
      for (int q = 0; q < 8; ++q)
        acc = fmaf(__uint_as_float(e[q].y), bf16_to_f32(h[q]), acc);
    }
    for (; j + 4 <= re; j += 4) {
      uint2 e[4];
      #pragma unroll
      for (int q = 0; q < 4; ++q) e[q] = sbuf[j + q];
      unsigned short h[4];
      #pragma unroll
      for (int q = 0; q < 4; ++q)
        h[q] = *(const unsigned short*)(xwb + e[q].x);
      #pragma unroll
      for (int q = 0; q < 4; ++q)
        acc = fmaf(__uint_as_float(e[q].y), bf16_to_f32(h[q]), acc);
    }
    for (; j < re; ++j) {
      const uint2 e = sbuf[j];
      acc = fmaf(__uint_as_float(e.y),
                 bf16_to_f32(*(const unsigned short*)(xwb + e.x)), acc);
    }
    const int grow = b * bd + r;
    if (grow < ndst) out[(size_t)grow * DIM + lane] = fmaxf(acc, 0.f);
  }
}

extern "C" void kernel_launch(void* const* d_in, const int* in_sizes, int n_in,
                              void* d_out, int out_size, void* d_ws, size_t ws_size,
                              hipStream_t stream) {
  const float* user_x      = (const float*)d_in[0];
  const float* item_x      = (const float*)d_in[1];
  const float* user_weight = (const float*)d_in[2];
  const float* item_weight = (const float*)d_in[3];
  const int*   ui_rows     = (const int*)d_in[4];
  const int*   ui_cols     = (const int*)d_in[5];
  const float* ui_vals     = (const float*)d_in[6];

  float* out_user = (float*)d_out;
  float* out_item = (float*)d_out + (size_t)N_USERS * DIM;

  // ---- workspace layout (fixed-capacity bucket regions) ------------------
  unsigned short* xw_user = (unsigned short*)d_ws;               // 6.4M bf16
  unsigned short* xw_item = xw_user + (size_t)N_USERS * DIM;     // 3.2M bf16
  uint2* binA = (uint2*)(xw_item + (size_t)N_ITEMS * DIM);       // user buckets
  uint2* binB = binA + (size_t)NBU * CAP;                        // item buckets
  int*   cur_u = (int*)(binB + (size_t)NBI * CAP);               // NBU
  int*   cur_i = cur_u + NBU;                                    // NBI
  // total ~49.7 MB

  // 0. Zero offset-based bucket cursors (~6 KB).
  hipMemsetAsync(cur_u, 0, (NBU + NBI) * sizeof(int), stream);

  // 1. Merged GEMM + binning (gemm blocks first — r17 proven order).
  prep_kernel<<<PREP_GU + PREP_GI + PREP_BIN, 512, 0, stream>>>(
      user_x, user_weight, xw_user, item_x, item_weight, xw_item,
      ui_rows, ui_cols, ui_vals, cur_u, cur_i, binA, binB);

  // 2. Fused fine-sort + SpMM + ReLU (256-thread blocks, 7 blocks/CU).
  sort_spmm_kernel<<<NBU + NBI, 256, 0, stream>>>(
      binA, cur_u, xw_item, out_user,
      binB, cur_i, xw_user, out_item);
}

// Round 21
// 111.753 us; speedup vs baseline: 1.0519x; 1.0519x over previous
//
#include <hip/hip_runtime.h>
#include <hip/hip_bf16.h>

#define N_USERS 100000
#define N_ITEMS 50000
#define NNZ_EDGES 1600000
#define DIM 64

#define BSHIFT_U 7
#define BD_U 128                             // user dests per coarse bucket
#define BSHIFT_I 6
#define BD_I 64                              // item dests per coarse bucket
#define NBU ((N_USERS + BD_U - 1) / BD_U)    // 782
#define NBI ((N_ITEMS + BD_I - 1) / BD_I)    // 782
#define NB_MAX 782
#define TILE 4096                            // edges per binning tile (8/thread @512)
#define CAP 2432                             // bucket capacity (mean 2048 + 8.5 sigma)

#define PREP_GU ((N_USERS + 127) / 128)      // 782
#define PREP_GI ((N_ITEMS + 127) / 128)      // 391
#define PREP_BIN ((NNZ_EDGES + TILE - 1) / TILE) // 391

// Record layout (binned): pk = (dst_local << 25) | (src_byte_off) with
// src_byte_off = src*128 in bits 7..24. After the in-LDS sort the dl bits
// are stripped; gather addr = (char*)xw + s*16 + e.x (16B-aligned).

__device__ inline unsigned short f32_to_bf16(float f) {
  unsigned u = __float_as_uint(f);
  unsigned r = (u + 0x7FFFu + ((u >> 16) & 1u)) >> 16;  // RNE
  return (unsigned short)r;
}
__device__ inline float bf16_lo(unsigned u) { return __uint_as_float(u << 16); }
__device__ inline float bf16_hi(unsigned u) { return __uint_as_float(u & 0xFFFF0000u); }

// ---------------------------------------------------------------------------
// PREP: merged dense GEMM + two-direction binning in ONE dispatch (gemm
// blocks first — proven r17 order).
// ---------------------------------------------------------------------------
__global__ __launch_bounds__(512) void prep_kernel(
    const float* __restrict__ Xu, const float* __restrict__ Wu,
    unsigned short* __restrict__ Yu,
    const float* __restrict__ Xi, const float* __restrict__ Wi,
    unsigned short* __restrict__ Yi,
    const int* __restrict__ rows, const int* __restrict__ cols,
    const float* __restrict__ vals,
    int* __restrict__ cur_u, int* __restrict__ cur_i,
    uint2* __restrict__ out_u, uint2* __restrict__ out_i) {
  __shared__ char smem[49152];
  const int tid = threadIdx.x, lane = tid & 63, wid = tid >> 6;

  if (blockIdx.x < PREP_GU + PREP_GI) {
    // ------------------------- GEMM path ---------------------------------
    float* sW = (float*)smem;                       // [64][64] 16 KB
    float* sXTb = (float*)(smem + 16384);           // [2][64][64] 32 KB
    const int sub = tid >> 8;
    const int stid = tid & 255;

    const float* X; const float* W; unsigned short* Y; int nrows, row_base;
    if (blockIdx.x < PREP_GU) {
      X = Xu; W = Wu; Y = Yu; nrows = N_USERS;
      row_base = blockIdx.x * 128 + sub * 64;
    } else {
      X = Xi; W = Wi; Y = Yi; nrows = N_ITEMS;
      row_base = (blockIdx.x - PREP_GU) * 128 + sub * 64;
    }

    {
      const float4* Wv = (const float4*)W;
      float4* sWv = (float4*)sW;
      #pragma unroll
      for (int i = 0; i < 2; ++i) sWv[tid + i * 512] = Wv[tid + i * 512];
    }
    float* sXT = sXTb + sub * 64 * 64;              // [k][row]
    {
      const int r = stid & 63;
      const int k0 = (stid >> 6) * 16;
      const int grow = row_base + r;
      #pragma unroll
      for (int i = 0; i < 4; ++i) {
        float4 v = make_float4(0.f, 0.f, 0.f, 0.f);
        if (grow < nrows) v = ((const float4*)(X + (size_t)grow * DIM + k0))[i];
        sXT[(k0 + i * 4 + 0) * 64 + r] = v.x;
        sXT[(k0 + i * 4 + 1) * 64 + r] = v.y;
        sXT[(k0 + i * 4 + 2) * 64 + r] = v.z;
        sXT[(k0 + i * 4 + 3) * 64 + r] = v.w;
      }
    }
    __syncthreads();

    const int tx = stid & 15;
    const int ty = stid >> 4;
    float acc[4][4] = {{0.f}};

    #pragma unroll 8
    for (int k = 0; k < 64; ++k) {
      const float4 a = *(const float4*)&sXT[k * 64 + ty * 4];
      const float4 b = *(const float4*)&sW[k * 64 + tx * 4];
      acc[0][0] = fmaf(a.x, b.x, acc[0][0]);
      acc[0][1] = fmaf(a.x, b.y, acc[0][1]);
      acc[0][2] = fmaf(a.x, b.z, acc[0][2]);
      acc[0][3] = fmaf(a.x, b.w, acc[0][3]);
      acc[1][0] = fmaf(a.y, b.x, acc[1][0]);
      acc[1][1] = fmaf(a.y, b.y, acc[1][1]);
      acc[1][2] = fmaf(a.y, b.z, acc[1][2]);
      acc[1][3] = fmaf(a.y, b.w, acc[1][3]);
      acc[2][0] = fmaf(a.z, b.x, acc[2][0]);
      acc[2][1] = fmaf(a.z, b.y, acc[2][1]);
      acc[2][2] = fmaf(a.z, b.z, acc[2][2]);
      acc[2][3] = fmaf(a.z, b.w, acc[2][3]);
      acc[3][0] = fmaf(a.w, b.x, acc[3][0]);
      acc[3][1] = fmaf(a.w, b.y, acc[3][1]);
      acc[3][2] = fmaf(a.w, b.z, acc[3][2]);
      acc[3][3] = fmaf(a.w, b.w, acc[3][3]);
    }

    #pragma unroll
    for (int r = 0; r < 4; ++r) {
      const int grow = row_base + ty * 4 + r;
      if (grow < nrows) {
        ushort4 o;
        o.x = f32_to_bf16(acc[r][0]);
        o.y = f32_to_bf16(acc[r][1]);
        o.z = f32_to_bf16(acc[r][2]);
        o.w = f32_to_bf16(acc[r][3]);
        *(ushort4*)(Y + (size_t)grow * DIM + tx * 4) = o;
      }
    }
    return;
  }

  // --------------------------- binning path ------------------------------
  uint2* sbuf = (uint2*)smem;                          // 32 KB
  unsigned short* sbk = (unsigned short*)(smem + 32768); // 8 KB
  int* sh   = (int*)(smem + 40960);
  int* scnt = (int*)(smem + 44088);
  int* s_w  = (int*)(smem + 47232);                    // 9 ints

  const int tbase = (blockIdx.x - (PREP_GU + PREP_GI)) * TILE;
  const int total = min(TILE, NNZ_EDGES - tbase);

  int er[8], ec[8]; unsigned ev[8];
  #pragma unroll
  for (int k = 0; k < 8; ++k) {
    const int i = tbase + k * 512 + tid;
    if (i < NNZ_EDGES) {
      er[k] = rows[i];
      ec[k] = cols[i];
      ev[k] = __float_as_uint(vals[i]);
    } else {
      er[k] = -1; ec[k] = 0; ev[k] = 0;
    }
  }

#define BIN_PHASE(BKEXPR, PKEXPR, NB, CUR, OUT)                                \
  {                                                                            \
    for (int j = tid; j < (NB); j += 512) sh[j] = 0;                           \
    __syncthreads();                                                           \
    int bk[8]; unsigned pk[8];                                                 \
    _Pragma("unroll")                                                          \
    for (int k = 0; k < 8; ++k) {                                              \
      if (er[k] >= 0) {                                                        \
        bk[k] = (BKEXPR); pk[k] = (PKEXPR);                                    \
        atomicAdd(&sh[bk[k]], 1);                                              \
      } else { bk[k] = -1; pk[k] = 0; }                                        \
    }                                                                          \
    __syncthreads();                                                           \
    int carry = 0;                                                             \
    for (int cb = 0; cb < (NB); cb += 512) {                                   \
      const int idx = cb + tid;                                                \
      const int x = (idx < (NB)) ? sh[idx] : 0;                                \
      int incl = x;                                                            \
      _Pragma("unroll")                                                        \
      for (int d = 1; d < 64; d <<= 1) {                                       \
        int t = __shfl_up(incl, d);                                            \
        if (lane >= d) incl += t;                                              \
      }                                                                        \
      if (lane == 63) s_w[wid] = incl;                                         \
      __syncthreads();                                                         \
      if (tid == 0) {                                                          \
        int a = 0;                                                             \
        _Pragma("unroll")                                                      \
        for (int w = 0; w < 8; ++w) { const int t = s_w[w]; s_w[w] = a; a += t; } \
        s_w[8] = a;                                                            \
      }                                                                        \
      __syncthreads();                                                         \
      const int excl = carry + s_w[wid] + incl - x;                            \
      if (idx < (NB)) { scnt[idx] = x; sh[idx] = excl; }                       \
      carry += s_w[8];                                                         \
      __syncthreads();                                                         \
    }                                                                          \
    _Pragma("unroll")                                                          \
    for (int k = 0; k < 8; ++k) {                                              \
      if (bk[k] >= 0) {                                                        \
        const int p = atomicAdd(&sh[bk[k]], 1);                                \
        sbuf[p] = make_uint2(pk[k], ev[k]);                                    \
        sbk[p] = (unsigned short)bk[k];                                        \
      }                                                                        \
    }                                                                          \
    __syncthreads();                                                           \
    for (int idx = tid; idx < (NB); idx += 512) {                              \
      const int c = scnt[idx];                                                 \
      const int excl = sh[idx] - c;                                            \
      int g = 0;                                                               \
      if (c > 0) g = atomicAdd(&(CUR)[idx], c);                                \
      scnt[idx] = excl;                                                        \
      sh[idx] = idx * CAP + g;                                                 \
    }                                                                          \
    __syncthreads();                                                           \
    for (int p = tid; p < total; p += 512) {                                   \
      const int b = sbk[p];                                                    \
      (OUT)[sh[b] + (p - scnt[b])] = sbuf[p];                                  \
    }                                                                          \
    __syncthreads();                                                           \
  }

  BIN_PHASE(er[k] >> BSHIFT_U,
            ((unsigned)(er[k] & (BD_U - 1)) << 25) | ((unsigned)ec[k] << 7),
            NBU, cur_u, out_u)
  BIN_PHASE(ec[k] >> BSHIFT_I,
            ((unsigned)(ec[k] & (BD_I - 1)) << 25) | ((unsigned)er[k] << 7),
            NBI, cur_i, out_i)
#undef BIN_PHASE
}

// ---------------------------------------------------------------------------
// Fused fine-sort + SpMM + ReLU. 512-thread blocks (r17-proven sort).
// NEW GATHER SHAPE: 8 lanes per edge (lane = (g,s)); per wave-instruction
// ONE uint4 load fetches 16B x 64 lanes = 8 full source rows (8 edges).
// Lane accumulates 8 features (s*8..s*8+7) over its edge-slot g; row end:
// shfl_xor reduce over strides 8/16/32, lanes g==0 store two float4.
// ---------------------------------------------------------------------------
__global__ __launch_bounds__(512) void sort_spmm_kernel(
    const uint2* __restrict__ bin_u, const int* __restrict__ cur_u,
    const unsigned short* __restrict__ xw_item, float* __restrict__ out_user,
    const uint2* __restrict__ bin_i, const int* __restrict__ cur_i,
    const unsigned short* __restrict__ xw_user, float* __restrict__ out_item) {
  __shared__ uint2 sbuf[CAP];     // 19.5 KB (sorted records, dl stripped)
  __shared__ int cnt[128];        // hist -> scatter cursor -> row end
  __shared__ int roff[128];       // row start
  __shared__ int s_w[2];
  const int tid = threadIdx.x;
  const int lane = tid & 63, wid = tid >> 6;

  const uint2* bin; const int* cur; const unsigned short* xw; float* out;
  int b, bd, ndst;
  if (blockIdx.x < NBU) {
    b = blockIdx.x; bd = BD_U; ndst = N_USERS;
    bin = bin_u; cur = cur_u; xw = xw_item; out = out_user;
  } else {
    b = blockIdx.x - NBU; bd = BD_I; ndst = N_ITEMS;
    bin = bin_i; cur = cur_i; xw = xw_user; out = out_item;
  }
  const int beg = b * CAP;
  const int n = min(cur[b], CAP);   // cursor holds the COUNT (offset-based)

  if (tid < 128) cnt[tid] = 0;
  __syncthreads();

  // Stage records in registers + LDS histogram of local dests.
  uint2 rg[5];
  #pragma unroll
  for (int k = 0; k < 5; ++k) {
    const int i = k * 512 + tid;
    if (i < n) {
      rg[k] = bin[beg + i];
      atomicAdd(&cnt[rg[k].x >> 25], 1);
    } else {
      rg[k] = make_uint2(0u, 0u);
    }
  }
  __syncthreads();

  // Exclusive scan of cnt[0..bd) in the first 128 threads (bd <= 128).
  int x = 0, incl = 0;
  if (tid < 128) {
    x = (tid < bd) ? cnt[tid] : 0;
    incl = x;
    #pragma unroll
    for (int d = 1; d < 64; d <<= 1) {
      int t = __shfl_up(incl, d);
      if (lane >= d) incl += t;
    }
    if (lane == 63) s_w[wid] = incl;
  }
  __syncthreads();
  if (tid == 0) {
    const int t0 = s_w[0];
    s_w[0] = 0;
    s_w[1] = t0;
  }
  __syncthreads();
  if (tid < 128) {
    const int excl = s_w[wid] + incl - x;
    if (tid < bd) {
      roff[tid] = excl;   // row start
      cnt[tid] = excl;    // scatter cursor (becomes row end after scatter)
    }
  }
  __syncthreads();

  // Scatter registers -> sorted LDS buffer, stripping the dl bits.
  #pragma unroll
  for (int k = 0; k < 5; ++k) {
    const int i = k * 512 + tid;
    if (i < n) {
      const int p = atomicAdd(&cnt[rg[k].x >> 25], 1);
      sbuf[p] = make_uint2(rg[k].x & 0x01FFFF80u, rg[k].y);
    }
  }
  __syncthreads();

  // SpMM: wave w handles rows w, w+8, ... ; 8 lanes/edge, 8 edges/wave-instr.
  const int g = lane >> 3;        // edge slot 0..7
  const int s = lane & 7;         // feature sub-block: features s*8 .. s*8+7
  const char* __restrict__ xwb = (const char*)xw + s * 16;

  for (int r = wid; r < bd; r += 8) {
    const int rb = roff[r], re = cnt[r];
    float a0 = 0.f, a1 = 0.f, a2 = 0.f, a3 = 0.f;
    float a4 = 0.f, a5 = 0.f, a6 = 0.f, a7 = 0.f;

    int j = rb;
    // 2-deep pipeline: 16 edges, all slots in-bounds (j+15 < re).
    for (; j + 16 <= re; j += 16) {
      const uint2 ea = sbuf[j + g];
      const uint2 eb = sbuf[j + 8 + g];
      const uint4 ga = *(const uint4*)(xwb + ea.x);
      const uint4 gb = *(const uint4*)(xwb + eb.x);
      const float va = __uint_as_float(ea.y);
      const float vb = __uint_as_float(eb.y);
      a0 = fmaf(va, bf16_lo(ga.x), a0);  a1 = fmaf(va, bf16_hi(ga.x), a1);
      a2 = fmaf(va, bf16_lo(ga.y), a2);  a3 = fmaf(va, bf16_hi(ga.y), a3);
      a4 = fmaf(va, bf16_lo(ga.z), a4);  a5 = fmaf(va, bf16_hi(ga.z), a5);
      a6 = fmaf(va, bf16_lo(ga.w), a6);  a7 = fmaf(va, bf16_hi(ga.w), a7);
      a0 = fmaf(vb, bf16_lo(gb.x), a0);  a1 = fmaf(vb, bf16_hi(gb.x), a1);
      a2 = fmaf(vb, bf16_lo(gb.y), a2);  a3 = fmaf(vb, bf16_hi(gb.y), a3);
      a4 = fmaf(vb, bf16_lo(gb.z), a4);  a5 = fmaf(vb, bf16_hi(gb.z), a5);
      a6 = fmaf(vb, bf16_lo(gb.w), a6);  a7 = fmaf(vb, bf16_hi(gb.w), a7);
    }
    // Predicated 8-edge tail steps.
    for (; j < re; j += 8) {
      const bool valid = (j + g) < re;
      uint2 e = make_uint2(0u, 0u);
      if (valid) e = sbuf[j + g];
      const uint4 gv = *(const uint4*)(xwb + e.x);
      const float v = valid ? __uint_as_float(e.y) : 0.f;
      a0 = fmaf(v, bf16_lo(gv.x), a0);  a1 = fmaf(v, bf16_hi(gv.x), a1);
      a2 = fmaf(v, bf16_lo(gv.y), a2);  a3 = fmaf(v, bf16_hi(gv.y), a3);
      a4 = fmaf(v, bf16_lo(gv.z), a4);  a5 = fmaf(v, bf16_hi(gv.z), a5);
      a6 = fmaf(v, bf16_lo(gv.w), a6);  a7 = fmaf(v, bf16_hi(gv.w), a7);
    }

    // Reduce across the 8 edge-slots (lane strides 8,16,32).
    #pragma unroll
    for (int d = 8; d < 64; d <<= 1) {
      a0 += __shfl_xor(a0, d);  a1 += __shfl_xor(a1, d);
      a2 += __shfl_xor(a2, d);  a3 += __shfl_xor(a3, d);
      a4 += __shfl_xor(a4, d);  a5 += __shfl_xor(a5, d);
      a6 += __shfl_xor(a6, d);  a7 += __shfl_xor(a7, d);
    }

    const int grow = b * bd + r;
    if (g == 0 && grow < ndst) {
      float4 o0, o1;
      o0.x = fmaxf(a0, 0.f); o0.y = fmaxf(a1, 0.f);
      o0.z = fmaxf(a2, 0.f); o0.w = fmaxf(a3, 0.f);
      o1.x = fmaxf(a4, 0.f); o1.y = fmaxf(a5, 0.f);
      o1.z = fmaxf(a6, 0.f); o1.w = fmaxf(a7, 0.f);
      float* op = out + (size_t)grow * DIM + s * 8;
      *(float4*)op = o0;
      *(float4*)(op + 4) = o1;
    }
  }
}

extern "C" void kernel_launch(void* const* d_in, const int* in_sizes, int n_in,
                              void* d_out, int out_size, void* d_ws, size_t ws_size,
                              hipStream_t stream) {
  const float* user_x      = (const float*)d_in[0];
  const float* item_x      = (const float*)d_in[1];
  const float* user_weight = (const float*)d_in[2];
  const float* item_weight = (const float*)d_in[3];
  const int*   ui_rows     = (const int*)d_in[4];
  const int*   ui_cols     = (const int*)d_in[5];
  const float* ui_vals     = (const float*)d_in[6];

  float* out_user = (float*)d_out;
  float* out_item = (float*)d_out + (size_t)N_USERS * DIM;

  // ---- workspace layout (fixed-capacity bucket regions) ------------------
  unsigned short* xw_user = (unsigned short*)d_ws;               // 6.4M bf16
  unsigned short* xw_item = xw_user + (size_t)N_USERS * DIM;     // 3.2M bf16
  uint2* binA = (uint2*)(xw_item + (size_t)N_ITEMS * DIM);       // user buckets
  uint2* binB = binA + (size_t)NBU * CAP;                        // item buckets
  int*   cur_u = (int*)(binB + (size_t)NBI * CAP);               // NBU
  int*   cur_i = cur_u + NBU;                                    // NBI
  // total ~49.7 MB

  // 0. Zero offset-based bucket cursors (~6 KB).
  hipMemsetAsync(cur_u, 0, (NBU + NBI) * sizeof(int), stream);

  // 1. Merged GEMM + binning (gemm blocks first — proven order).
  prep_kernel<<<PREP_GU + PREP_GI + PREP_BIN, 512, 0, stream>>>(
      user_x, user_weight, xw_user, item_x, item_weight, xw_item,
      ui_rows, ui_cols, ui_vals, cur_u, cur_i, binA, binB);

  // 2. Fused fine-sort + SpMM + ReLU (8-lane-per-edge gather shape).
  sort_spmm_kernel<<<NBU + NBI, 512, 0, stream>>>(
      binA, cur_u, xw_item, out_user,
      binB, cur_i, xw_user, out_item);
}